// Round 7
// baseline (718.044 us; speedup 1.0000x reference)
//
#include <hip/hip_runtime.h>

#define NN 50000
#define TT 10
#define EE 1000000

#define NB 512         // dst buckets (node ranges)
#define BN 98          // nodes per bucket (NB*BN = 50176 >= NN)
#define CHUNK 2048     // edges per sort chunk
#define NCHUNK 489     // ceil(EE/CHUNK)
#define CHPAD 512      // padded chunk slots per (t,b) hist row
#define KPT (CHUNK / 256)

__device__ __forceinline__ float sigmoidf_(float v) { return 1.0f / (1.0f + __expf(-v)); }
__device__ __forceinline__ float reluf_(float v) { return v > 0.0f ? v : 0.0f; }

__device__ __forceinline__ float4 ld4_(const float* __restrict__ p) {
    return *reinterpret_cast<const float4*>(p);
}
__device__ __forceinline__ void fma_row8(float* acc, const float* __restrict__ w, float f) {
    float4 a = ld4_(w), b = ld4_(w + 4);
    acc[0] += f * a.x; acc[1] += f * a.y; acc[2] += f * a.z; acc[3] += f * a.w;
    acc[4] += f * b.x; acc[5] += f * b.y; acc[6] += f * b.z; acc[7] += f * b.w;
}

// Serial MLP1 (pre_kernel only).
__device__ __forceinline__ float mlp1_eval_g(const float* feat,
                                             const float* __restrict__ w1,
                                             const float* __restrict__ b1,
                                             const float* __restrict__ w2,
                                             const float* __restrict__ b2,
                                             const float* __restrict__ w3,
                                             const float* __restrict__ b3) {
    float h1[32];
#pragma unroll
    for (int j = 0; j < 32; ++j) h1[j] = b1[j];
#pragma unroll
    for (int i = 0; i < 9; ++i) {
        float f = feat[i];
#pragma unroll
        for (int j = 0; j < 32; ++j) h1[j] += f * w1[i * 32 + j];
    }
#pragma unroll
    for (int j = 0; j < 32; ++j) h1[j] = reluf_(h1[j]);
    float h2[32];
#pragma unroll
    for (int j = 0; j < 32; ++j) h2[j] = b2[j];
#pragma unroll
    for (int i = 0; i < 32; ++i) {
        float f = h1[i];
#pragma unroll
        for (int j = 0; j < 32; ++j) h2[j] += f * w2[i * 32 + j];
    }
    float acc = b3[0];
#pragma unroll
    for (int j = 0; j < 32; ++j) acc += reluf_(h2[j]) * w3[j];
    return sigmoidf_(acc);
}

// Pre-pass: x transposes (sorted path) + init hidden / msg_base(frame 0) / agg.
__global__ void pre_kernel(const float* __restrict__ x,
                           const float* __restrict__ w1, const float* __restrict__ b1,
                           const float* __restrict__ w2, const float* __restrict__ b2,
                           const float* __restrict__ w3, const float* __restrict__ b3,
                           float* __restrict__ hidden, float* __restrict__ msg_base,
                           float* __restrict__ agg,
                           float* __restrict__ x0T, float* __restrict__ x1T,
                           int sorted) {
    int g = blockIdx.x * blockDim.x + threadIdx.x;
    if (g >= NN) return;
    float x00;
    if (sorted) {
        const float2* xr = reinterpret_cast<const float2*>(x + (size_t)g * TT * 2);
        float x0v[TT], x1v[TT];
#pragma unroll
        for (int tt = 0; tt < TT; ++tt) { float2 p = xr[tt]; x0v[tt] = p.x; x1v[tt] = p.y; }
#pragma unroll
        for (int tt = 0; tt < TT; ++tt) { x0T[tt * NN + g] = x0v[tt]; x1T[tt * NN + g] = x1v[tt]; }
        x00 = x0v[0];
    } else {
        x00 = x[(size_t)g * TT * 2];
    }
    agg[g] = 0.0f;
    float feat[9];
    feat[0] = x00;
#pragma unroll
    for (int k = 0; k < 8; ++k) feat[1 + k] = 0.0f;
    msg_base[g] = mlp1_eval_g(feat, w1, b1, w2, b2, w3, b3);
#pragma unroll
    for (int k = 0; k < 8; ++k) hidden[g * 8 + k] = 0.0f;
}

// --- One-time 512-bucket counting sort of edges by dst range, all frames ---

// K1: per-chunk block, loop frames: LDS hist (4 wave replicas) -> chist counts.
__global__ __launch_bounds__(256) void hist_kernel(const int* __restrict__ ei,
                                                   unsigned* __restrict__ chist) {
    __shared__ unsigned h4[4][NB];
    const int c = blockIdx.x, tid = threadIdx.x, w = tid >> 6;
    for (int t = 0; t < TT; ++t) {
        for (int i = tid; i < 4 * NB; i += 256) (&h4[0][0])[i] = 0u;
        __syncthreads();
        const int* dstp = ei + (size_t)(TT + t) * EE;
#pragma unroll
        for (int k = 0; k < KPT; ++k) {
            int e = c * CHUNK + k * 256 + tid;
            if (e < EE) atomicAdd(&h4[w][(unsigned)dstp[e] / BN], 1u);
        }
        __syncthreads();
        for (int b2 = tid; b2 < NB; b2 += 256) {
            unsigned s = h4[0][b2] + h4[1][b2] + h4[2][b2] + h4[3][b2];
            chist[((size_t)(t * NB + b2)) * CHPAD + c] = s;
        }
        __syncthreads();
    }
}

// K2: in-place exclusive scan of each (t,b) row over chunks; row total out.
__global__ __launch_bounds__(64) void scan_kernel(unsigned* __restrict__ chist,
                                                  unsigned* __restrict__ total) {
    const int row = blockIdx.x;  // t*NB + b
    unsigned* r = chist + (size_t)row * CHPAD;
    const int lane = threadIdx.x;
    unsigned v[8];
    unsigned s = 0;
#pragma unroll
    for (int j = 0; j < 8; ++j) {
        int c = lane * 8 + j;
        unsigned xx = (c < NCHUNK) ? r[c] : 0u;
        v[j] = s; s += xx;
    }
    unsigned inc = s;
#pragma unroll
    for (int off = 1; off < 64; off <<= 1) {
        unsigned y = (unsigned)__shfl_up((int)inc, off);
        if (lane >= off) inc += y;
    }
    unsigned excl = inc - s;
#pragma unroll
    for (int j = 0; j < 8; ++j) {
        int c = lane * 8 + j;
        if (c < NCHUNK) r[c] = excl + v[j];
    }
    if (lane == 63) total[row] = inc;
}

// K2b: per-frame bucket bases.
__global__ void segbase_kernel(const unsigned* __restrict__ total,
                               unsigned* __restrict__ segBase) {
    int t = threadIdx.x;
    if (t < TT) {
        unsigned run = 0;
        for (int b = 0; b < NB; ++b) { segBase[t * NB + b] = run; run += total[t * NB + b]; }
    }
}

// K3: reorder. One block per chunk; ea row (all 10 frames) in registers (read
// once, coalesced); per frame: LDS hist -> LDS block scan -> LDS-staged
// reorder -> per-bucket-run coalesced write of packed int4 (src,dst,ea,0).
__global__ __launch_bounds__(256) void reorder_kernel(const int* __restrict__ ei,
                                                      const float* __restrict__ ea,
                                                      const unsigned* __restrict__ chist,
                                                      const unsigned* __restrict__ segBase,
                                                      int4* __restrict__ srt) {
    __shared__ int4 stg[CHUNK];
    __shared__ unsigned h4[4][NB];
    __shared__ unsigned lbase[NB], gbase[NB], cur[NB];
    __shared__ unsigned bscan[256];
    __shared__ unsigned cnt_s;
    const int c = blockIdx.x, tid = threadIdx.x, w = tid >> 6;

    float ear[KPT][TT];
#pragma unroll
    for (int k = 0; k < KPT; ++k) {
        int e = c * CHUNK + k * 256 + tid;
        if (e < EE) {
            const float2* row = reinterpret_cast<const float2*>(ea + (size_t)e * TT);
#pragma unroll
            for (int j2 = 0; j2 < 5; ++j2) {
                float2 p = row[j2];
                ear[k][2 * j2] = p.x; ear[k][2 * j2 + 1] = p.y;
            }
        } else {
#pragma unroll
            for (int tt = 0; tt < TT; ++tt) ear[k][tt] = 0.0f;
        }
    }

#pragma unroll
    for (int t = 0; t < TT; ++t) {
        for (int i = tid; i < 4 * NB; i += 256) (&h4[0][0])[i] = 0u;
        __syncthreads();
        const int* srcp = ei + (size_t)t * EE;
        const int* dstp = ei + (size_t)(TT + t) * EE;
        int se[KPT], de[KPT];
#pragma unroll
        for (int k = 0; k < KPT; ++k) {
            int e = c * CHUNK + k * 256 + tid;
            if (e < EE) {
                se[k] = srcp[e];
                de[k] = dstp[e];
                atomicAdd(&h4[w][(unsigned)de[k] / BN], 1u);
            } else {
                de[k] = -1; se[k] = 0;
            }
        }
        __syncthreads();
        // block scan over NB buckets (2 per thread)
        unsigned c0 = h4[0][2 * tid] + h4[1][2 * tid] + h4[2][2 * tid] + h4[3][2 * tid];
        unsigned c1 = h4[0][2 * tid + 1] + h4[1][2 * tid + 1] + h4[2][2 * tid + 1] + h4[3][2 * tid + 1];
        unsigned mys = c0 + c1;
        bscan[tid] = mys;
        __syncthreads();
        for (int off = 1; off < 256; off <<= 1) {
            unsigned vv = (tid >= off) ? bscan[tid - off] : 0u;
            __syncthreads();
            bscan[tid] += vv;
            __syncthreads();
        }
        unsigned excl = bscan[tid] - mys;
        lbase[2 * tid] = excl;           cur[2 * tid] = excl;
        lbase[2 * tid + 1] = excl + c0;  cur[2 * tid + 1] = excl + c0;
        if (tid == 255) cnt_s = bscan[255];
        for (int b2 = tid; b2 < NB; b2 += 256)
            gbase[b2] = segBase[t * NB + b2] + chist[((size_t)(t * NB + b2)) * CHPAD + c];
        __syncthreads();
#pragma unroll
        for (int k = 0; k < KPT; ++k) {
            if (de[k] >= 0) {
                unsigned b = (unsigned)de[k] / BN;
                unsigned slot = atomicAdd(&cur[b], 1u);
                stg[slot] = make_int4(se[k], de[k], __float_as_int(ear[k][t]), 0);
            }
        }
        __syncthreads();
        const unsigned cnt = cnt_s;
        int4* dstT = srt + (size_t)t * EE;
        for (unsigned i = tid; i < cnt; i += 256) {
            int4 rec = stg[i];
            unsigned b = (unsigned)rec.y / BN;
            dstT[gbase[b] + (i - lbase[b])] = rec;
        }
        __syncthreads();
    }
}

// Per-frame edge aggregation: one block per 98-node bucket; stream the
// bucket's sorted run, LDS-accumulate 98 floats, write agg directly.
__global__ __launch_bounds__(256) void edge_srt_kernel(const int4* __restrict__ srt,
                                                       const unsigned* __restrict__ segBase,
                                                       const unsigned* __restrict__ total,
                                                       const float* __restrict__ msg_base,
                                                       float* __restrict__ agg, int t) {
    __shared__ float acc[BN];
    const int b = blockIdx.x, tid = threadIdx.x;
    if (tid < BN) acc[tid] = 0.0f;
    __syncthreads();
    const unsigned base = segBase[t * NB + b];
    const unsigned cnt = total[t * NB + b];
    const int4* p = srt + (size_t)t * EE + base;
    const int nbase = b * BN;
    for (unsigned i = tid; i < cnt; i += 256) {
        int4 rec = p[i];
        atomicAdd(&acc[rec.y - nbase], msg_base[rec.x] * __int_as_float(rec.z));
    }
    __syncthreads();
    int n = nbase + tid;
    if (tid < BN && n < NN) agg[n] = acc[tid];
}

// Legacy fallback: device-atomic scatter.
__global__ void edge_kernel(const int* __restrict__ ei, const float* __restrict__ ea,
                            const float* __restrict__ msg_base, float* __restrict__ agg,
                            int t) {
    int g = blockIdx.x * blockDim.x + threadIdx.x;
    int e0 = g * 2;
    if (e0 >= EE) return;
    const int2 s = *reinterpret_cast<const int2*>(ei + (size_t)t * EE + e0);
    const int2 d = *reinterpret_cast<const int2*>(ei + (size_t)(TT + t) * EE + e0);
    atomicAdd(&agg[d.x], msg_base[s.x] * ea[(size_t)e0 * TT + t]);
    atomicAdd(&agg[d.y], msg_base[s.y] * ea[(size_t)(e0 + 1) * TT + t]);
}

// 4-lane-per-node node update; reads agg[n] scalar (fully pre-reduced).
template <int SORTED>
__global__ __launch_bounds__(256) void node4_kernel(
        const float* __restrict__ x,
        const float* __restrict__ x0T, const float* __restrict__ x1T,
        const float* __restrict__ m1w1, const float* __restrict__ m1b1,
        const float* __restrict__ m1w2, const float* __restrict__ m1b2,
        const float* __restrict__ m1w3, const float* __restrict__ m1b3,
        const float* __restrict__ m2w1, const float* __restrict__ m2b1,
        const float* __restrict__ m2w2, const float* __restrict__ m2b2,
        const float* __restrict__ ow1, const float* __restrict__ ob1,
        const float* __restrict__ ow2, const float* __restrict__ ob2,
        float* __restrict__ hidden, float* __restrict__ msg_base,
        float* __restrict__ agg, float* __restrict__ out, int t) {
    const int gid = blockIdx.x * 256 + threadIdx.x;
    const int n = gid >> 2;
    const int q = gid & 3;
    if (n >= NN) return;

    const float a = agg[n];
    const float x1 = SORTED ? x1T[t * NN + n] : x[(size_t)n * TT * 2 + t * 2 + 1];

    float2 hme = *reinterpret_cast<const float2*>(hidden + (size_t)n * 8 + q * 2);
    float hid[8];
    hid[0] = hme.x; hid[1] = hme.y;
    hid[2] = __shfl_xor(hid[0], 1); hid[3] = __shfl_xor(hid[1], 1);
    hid[4] = __shfl_xor(hid[0], 2); hid[5] = __shfl_xor(hid[1], 2);
    hid[6] = __shfl_xor(hid[2], 2); hid[7] = __shfl_xor(hid[3], 2);

    float acc[8];
    {
        float4 bA = ld4_(m2b1 + q * 8), bB = ld4_(m2b1 + q * 8 + 4);
        acc[0] = bA.x; acc[1] = bA.y; acc[2] = bA.z; acc[3] = bA.w;
        acc[4] = bB.x; acc[5] = bB.y; acc[6] = bB.z; acc[7] = bB.w;
    }
    fma_row8(acc, m2w1 + q * 8, x1);
#pragma unroll
    for (int g = 0; g < 4; ++g) {
        int rq = (q ^ g) * 2;
        fma_row8(acc, m2w1 + (size_t)(1 + rq) * 32 + q * 8, hid[g * 2 + 0]);
        fma_row8(acc, m2w1 + (size_t)(2 + rq) * 32 + q * 8, hid[g * 2 + 1]);
    }
    fma_row8(acc, m2w1 + (size_t)9 * 32 + q * 8, a);
    float u1[8];
#pragma unroll
    for (int jj = 0; jj < 8; ++jj) u1[jj] = reluf_(acc[jj]);

    float pk[8];
#pragma unroll
    for (int k = 0; k < 8; ++k) pk[k] = 0.0f;
#pragma unroll
    for (int jj = 0; jj < 8; ++jj)
        fma_row8(pk, m2w2 + (size_t)(q * 8 + jj) * 8, u1[jj]);
#pragma unroll
    for (int k = 0; k < 8; ++k) {
        pk[k] += __shfl_xor(pk[k], 1);
        pk[k] += __shfl_xor(pk[k], 2);
    }
    float hn[8];
    {
        float4 b2A = ld4_(m2b2), b2B = ld4_(m2b2 + 4);
        hn[0] = tanhf(reluf_(pk[0] + b2A.x));
        hn[1] = tanhf(reluf_(pk[1] + b2A.y));
        hn[2] = tanhf(reluf_(pk[2] + b2A.z));
        hn[3] = tanhf(reluf_(pk[3] + b2A.w));
        hn[4] = tanhf(reluf_(pk[4] + b2B.x));
        hn[5] = tanhf(reluf_(pk[5] + b2B.y));
        hn[6] = tanhf(reluf_(pk[6] + b2B.z));
        hn[7] = tanhf(reluf_(pk[7] + b2B.w));
    }
    if (q == 0) {
        *reinterpret_cast<float4*>(hidden + (size_t)n * 8)     = make_float4(hn[0], hn[1], hn[2], hn[3]);
        *reinterpret_cast<float4*>(hidden + (size_t)n * 8 + 4) = make_float4(hn[4], hn[5], hn[6], hn[7]);
    }

    float o1v[4];
    {
        float4 ob = ld4_(ob1 + q * 4);
        o1v[0] = ob.x; o1v[1] = ob.y; o1v[2] = ob.z; o1v[3] = ob.w;
    }
#pragma unroll
    for (int k = 0; k < 8; ++k) {
        float4 wv = ld4_(ow1 + k * 16 + q * 4);
        o1v[0] += hn[k] * wv.x; o1v[1] += hn[k] * wv.y;
        o1v[2] += hn[k] * wv.z; o1v[3] += hn[k] * wv.w;
    }
    {
        float4 w2v = ld4_(ow2 + q * 4);
        float oop = reluf_(o1v[0]) * w2v.x + reluf_(o1v[1]) * w2v.y +
                    reluf_(o1v[2]) * w2v.z + reluf_(o1v[3]) * w2v.w;
        oop += __shfl_xor(oop, 1);
        oop += __shfl_xor(oop, 2);
        if (q == 0) out[t * NN + n] = sigmoidf_(oop + ob2[0]);
    }

    if (t < TT - 1) {
        float feat0 = SORTED ? x0T[(t + 1) * NN + n] : x[(size_t)n * TT * 2 + (t + 1) * 2];
        float h1[8];
        {
            float4 bA = ld4_(m1b1 + q * 8), bB = ld4_(m1b1 + q * 8 + 4);
            h1[0] = bA.x; h1[1] = bA.y; h1[2] = bA.z; h1[3] = bA.w;
            h1[4] = bB.x; h1[5] = bB.y; h1[6] = bB.z; h1[7] = bB.w;
        }
        fma_row8(h1, m1w1 + q * 8, feat0);
#pragma unroll
        for (int k = 0; k < 8; ++k)
            fma_row8(h1, m1w1 + (size_t)(1 + k) * 32 + q * 8, hn[k]);
#pragma unroll
        for (int jj = 0; jj < 8; ++jj) h1[jj] = reluf_(h1[jj]);

        float h1x[32];
#pragma unroll
        for (int jj = 0; jj < 8; ++jj) h1x[jj] = h1[jj];
#pragma unroll
        for (int jj = 0; jj < 8; ++jj) h1x[8 + jj]  = __shfl_xor(h1x[jj], 1);
#pragma unroll
        for (int jj = 0; jj < 8; ++jj) h1x[16 + jj] = __shfl_xor(h1x[jj], 2);
#pragma unroll
        for (int jj = 0; jj < 8; ++jj) h1x[24 + jj] = __shfl_xor(h1x[8 + jj], 2);

        float acc8[8];
        {
            float4 bA = ld4_(m1b2 + q * 8), bB = ld4_(m1b2 + q * 8 + 4);
            acc8[0] = bA.x; acc8[1] = bA.y; acc8[2] = bA.z; acc8[3] = bA.w;
            acc8[4] = bB.x; acc8[5] = bB.y; acc8[6] = bB.z; acc8[7] = bB.w;
        }
#pragma unroll
        for (int g = 0; g < 4; ++g) {
            int rb = (q ^ g) * 8;
#pragma unroll
            for (int jj = 0; jj < 8; ++jj)
                fma_row8(acc8, m1w2 + (size_t)(rb + jj) * 32 + q * 8, h1x[g * 8 + jj]);
        }
        float s3;
        {
            float4 w3a = ld4_(m1w3 + q * 8), w3b = ld4_(m1w3 + q * 8 + 4);
            s3 = reluf_(acc8[0]) * w3a.x + reluf_(acc8[1]) * w3a.y +
                 reluf_(acc8[2]) * w3a.z + reluf_(acc8[3]) * w3a.w +
                 reluf_(acc8[4]) * w3b.x + reluf_(acc8[5]) * w3b.y +
                 reluf_(acc8[6]) * w3b.z + reluf_(acc8[7]) * w3b.w;
        }
        s3 += __shfl_xor(s3, 1);
        s3 += __shfl_xor(s3, 2);
        if (q == 0) {
            msg_base[n] = sigmoidf_(s3 + m1b3[0]);
            if (!SORTED) agg[n] = 0.0f;
        }
    }
}

extern "C" void kernel_launch(void* const* d_in, const int* in_sizes, int n_in,
                              void* d_out, int out_size, void* d_ws, size_t ws_size,
                              hipStream_t stream) {
    (void)in_sizes; (void)n_in; (void)out_size;
    const float* x    = (const float*)d_in[0];
    const int*   ei   = (const int*)d_in[1];
    const float* ea   = (const float*)d_in[2];
    const float* m1w1 = (const float*)d_in[3];
    const float* m1b1 = (const float*)d_in[4];
    const float* m1w2 = (const float*)d_in[5];
    const float* m1b2 = (const float*)d_in[6];
    const float* m1w3 = (const float*)d_in[7];
    const float* m1b3 = (const float*)d_in[8];
    const float* m2w1 = (const float*)d_in[9];
    const float* m2b1 = (const float*)d_in[10];
    const float* m2w2 = (const float*)d_in[11];
    const float* m2b2 = (const float*)d_in[12];
    const float* ow1  = (const float*)d_in[13];
    const float* ob1  = (const float*)d_in[14];
    const float* ow2  = (const float*)d_in[15];
    const float* ob2  = (const float*)d_in[16];
    float* out = (float*)d_out;

    // Workspace carve (16B-aligned chunks)
    char* wp = (char*)d_ws;
    float* hidden   = (float*)wp; wp += (size_t)NN * 8 * 4;       // 1.6 MB
    float* msg_base = (float*)wp; wp += (size_t)NN * 4;           // 200 KB
    float* agg      = (float*)wp; wp += (size_t)NN * 4;           // 200 KB
    float* x0T      = (float*)wp; wp += (size_t)NN * TT * 4;      // 2 MB
    float* x1T      = (float*)wp; wp += (size_t)NN * TT * 4;      // 2 MB
    int4*  srt      = (int4*)wp;  wp += (size_t)TT * EE * 16;     // 160 MB
    unsigned* chist   = (unsigned*)wp; wp += (size_t)TT * NB * CHPAD * 4;  // 42 MB
    unsigned* total   = (unsigned*)wp; wp += (size_t)TT * NB * 4;
    unsigned* segBase = (unsigned*)wp; wp += (size_t)TT * NB * 4;
    size_t need = (size_t)(wp - (char*)d_ws);

    int sorted = (ws_size >= need) ? 1 : 0;

    dim3 blk(256);
    int nodeBlocks  = (NN + 255) / 256;
    int node4Blocks = (NN * 4 + 255) / 256;
    int edgeBlocksLegacy = (EE / 2 + 255) / 256;

    pre_kernel<<<nodeBlocks, blk, 0, stream>>>(x, m1w1, m1b1, m1w2, m1b2, m1w3, m1b3,
                                               hidden, msg_base, agg, x0T, x1T, sorted);
    if (sorted) {
        hist_kernel<<<NCHUNK, blk, 0, stream>>>(ei, chist);
        scan_kernel<<<TT * NB, dim3(64), 0, stream>>>(chist, total);
        segbase_kernel<<<1, dim3(64), 0, stream>>>(total, segBase);
        reorder_kernel<<<NCHUNK, blk, 0, stream>>>(ei, ea, chist, segBase, srt);
    }
    for (int t = 0; t < TT; ++t) {
        if (sorted) {
            edge_srt_kernel<<<NB, blk, 0, stream>>>(srt, segBase, total, msg_base, agg, t);
            node4_kernel<1><<<node4Blocks, blk, 0, stream>>>(
                x, x0T, x1T,
                m1w1, m1b1, m1w2, m1b2, m1w3, m1b3,
                m2w1, m2b1, m2w2, m2b2,
                ow1, ob1, ow2, ob2,
                hidden, msg_base, agg, out, t);
        } else {
            edge_kernel<<<edgeBlocksLegacy, blk, 0, stream>>>(ei, ea, msg_base, agg, t);
            node4_kernel<0><<<node4Blocks, blk, 0, stream>>>(
                x, x0T, x1T,
                m1w1, m1b1, m1w2, m1b2, m1w3, m1b3,
                m2w1, m2b1, m2w2, m2b2,
                ow1, ob1, ow2, ob2,
                hidden, msg_base, agg, out, t);
        }
    }
}

// Round 8
// 593.910 us; speedup vs baseline: 1.2090x; 1.2090x over previous
//
#include <hip/hip_runtime.h>

#define NN 50000
#define TT 10
#define EE 1000000

#define NB 391         // dst buckets; bucket = dst >> 7
#define BN 128         // nodes per bucket (NB*BN = 50048 >= NN)
#define NBP 512        // padded bucket slots for the block scan
#define CAP 3072       // region slots per (t,bucket); mean 2558, sigma 50 -> 10 sigma
#define CHUNK 2048
#define NCHUNK 489     // ceil(EE/CHUNK)
#define KPT (CHUNK / 256)
#define SPILLCAP 8192

__device__ __forceinline__ float sigmoidf_(float v) { return 1.0f / (1.0f + __expf(-v)); }
__device__ __forceinline__ float reluf_(float v) { return v > 0.0f ? v : 0.0f; }

__device__ __forceinline__ float4 ld4_(const float* __restrict__ p) {
    return *reinterpret_cast<const float4*>(p);
}
__device__ __forceinline__ void fma_row8(float* acc, const float* __restrict__ w, float f) {
    float4 a = ld4_(w), b = ld4_(w + 4);
    acc[0] += f * a.x; acc[1] += f * a.y; acc[2] += f * a.z; acc[3] += f * a.w;
    acc[4] += f * b.x; acc[5] += f * b.y; acc[6] += f * b.z; acc[7] += f * b.w;
}

// Serial MLP1 (pre_kernel only).
__device__ __forceinline__ float mlp1_eval_g(const float* feat,
                                             const float* __restrict__ w1,
                                             const float* __restrict__ b1,
                                             const float* __restrict__ w2,
                                             const float* __restrict__ b2,
                                             const float* __restrict__ w3,
                                             const float* __restrict__ b3) {
    float h1[32];
#pragma unroll
    for (int j = 0; j < 32; ++j) h1[j] = b1[j];
#pragma unroll
    for (int i = 0; i < 9; ++i) {
        float f = feat[i];
#pragma unroll
        for (int j = 0; j < 32; ++j) h1[j] += f * w1[i * 32 + j];
    }
#pragma unroll
    for (int j = 0; j < 32; ++j) h1[j] = reluf_(h1[j]);
    float h2[32];
#pragma unroll
    for (int j = 0; j < 32; ++j) h2[j] = b2[j];
#pragma unroll
    for (int i = 0; i < 32; ++i) {
        float f = h1[i];
#pragma unroll
        for (int j = 0; j < 32; ++j) h2[j] += f * w2[i * 32 + j];
    }
    float acc = b3[0];
#pragma unroll
    for (int j = 0; j < 32; ++j) acc += reluf_(h2[j]) * w3[j];
    return sigmoidf_(acc);
}

// Pre-pass: x transposes (sorted) + init hidden/msg_base/agg + zero gcnt/spill.
__global__ void pre_kernel(const float* __restrict__ x,
                           const float* __restrict__ w1, const float* __restrict__ b1,
                           const float* __restrict__ w2, const float* __restrict__ b2,
                           const float* __restrict__ w3, const float* __restrict__ b3,
                           float* __restrict__ hidden, float* __restrict__ msg_base,
                           float* __restrict__ agg,
                           float* __restrict__ x0T, float* __restrict__ x1T,
                           unsigned* __restrict__ gcnt, unsigned* __restrict__ spillCnt,
                           int sorted) {
    int g = blockIdx.x * blockDim.x + threadIdx.x;
    if (g < NB * TT) gcnt[g] = 0u;
    if (g == 0) spillCnt[0] = 0u;
    if (g >= NN) return;
    float x00;
    if (sorted) {
        const float2* xr = reinterpret_cast<const float2*>(x + (size_t)g * TT * 2);
        float x0v[TT], x1v[TT];
#pragma unroll
        for (int tt = 0; tt < TT; ++tt) { float2 p = xr[tt]; x0v[tt] = p.x; x1v[tt] = p.y; }
#pragma unroll
        for (int tt = 0; tt < TT; ++tt) { x0T[tt * NN + g] = x0v[tt]; x1T[tt * NN + g] = x1v[tt]; }
        x00 = x0v[0];
    } else {
        x00 = x[(size_t)g * TT * 2];
    }
    agg[g] = 0.0f;
    float feat[9];
    feat[0] = x00;
#pragma unroll
    for (int k = 0; k < 8; ++k) feat[1 + k] = 0.0f;
    msg_base[g] = mlp1_eval_g(feat, w1, b1, w2, b2, w3, b3);
#pragma unroll
    for (int k = 0; k < 8; ++k) hidden[g * 8 + k] = 0.0f;
}

// One-time reorder: grid (t fast, chunk). Per block: LDS hist of its 2048
// edges -> block scan -> one global atomicAdd per bucket grabs region space
// -> LDS-staged compaction -> coalesced run write-out of int4 (src,dst,ea,0).
__global__ __launch_bounds__(256) void reorder_kernel(const int* __restrict__ ei,
                                                      const float* __restrict__ ea,
                                                      unsigned* __restrict__ gcnt,
                                                      int4* __restrict__ regions,
                                                      int4* __restrict__ spill,
                                                      unsigned* __restrict__ spillCnt) {
    __shared__ int4 stg[CHUNK];
    __shared__ unsigned h4[4][NBP];
    __shared__ unsigned lbase[NBP], cur[NBP], gbase[NBP];
    __shared__ unsigned bscan[256];
    __shared__ unsigned cnt_s;
    const int t = blockIdx.x, c = blockIdx.y;
    const int tid = threadIdx.x, w = tid >> 6;

    for (int i = tid; i < 4 * NBP; i += 256) (&h4[0][0])[i] = 0u;
    __syncthreads();

    const int* srcp = ei + (size_t)t * EE;
    const int* dstp = ei + (size_t)(TT + t) * EE;
    int se[KPT], de[KPT];
    float ev[KPT];
#pragma unroll
    for (int k = 0; k < KPT; ++k) {
        int e = c * CHUNK + k * 256 + tid;
        if (e < EE) {
            se[k] = srcp[e];
            de[k] = dstp[e];
            ev[k] = ea[(size_t)e * TT + t];  // L2-shared across the 10 t-blocks of chunk c
            atomicAdd(&h4[w][(unsigned)de[k] >> 7], 1u);
        } else {
            de[k] = -1; se[k] = 0; ev[k] = 0.0f;
        }
    }
    __syncthreads();

    // block scan over NBP buckets, 2 per thread
    unsigned c0 = h4[0][2 * tid] + h4[1][2 * tid] + h4[2][2 * tid] + h4[3][2 * tid];
    unsigned c1 = h4[0][2 * tid + 1] + h4[1][2 * tid + 1] + h4[2][2 * tid + 1] + h4[3][2 * tid + 1];
    unsigned mys = c0 + c1;
    bscan[tid] = mys;
    __syncthreads();
    for (int off = 1; off < 256; off <<= 1) {
        unsigned vv = (tid >= off) ? bscan[tid - off] : 0u;
        __syncthreads();
        bscan[tid] += vv;
        __syncthreads();
    }
    unsigned excl = bscan[tid] - mys;
    lbase[2 * tid] = excl;           cur[2 * tid] = excl;
    lbase[2 * tid + 1] = excl + c0;  cur[2 * tid + 1] = excl + c0;
    if (tid == 255) cnt_s = bscan[255];
    {
        int b0 = 2 * tid, b1 = 2 * tid + 1;
        gbase[b0] = (b0 < NB) ? atomicAdd(&gcnt[t * NB + b0], c0) : 0u;
        gbase[b1] = (b1 < NB) ? atomicAdd(&gcnt[t * NB + b1], c1) : 0u;
    }
    __syncthreads();

#pragma unroll
    for (int k = 0; k < KPT; ++k) {
        if (de[k] >= 0) {
            unsigned b = (unsigned)de[k] >> 7;
            unsigned slot = atomicAdd(&cur[b], 1u);
            stg[slot] = make_int4(se[k], de[k], __float_as_int(ev[k]), 0);
        }
    }
    __syncthreads();

    const unsigned cnt = cnt_s;
    for (unsigned i = tid; i < cnt; i += 256) {
        int4 rec = stg[i];
        unsigned b = (unsigned)rec.y >> 7;
        unsigned g = gbase[b] + (i - lbase[b]);
        if (g < CAP) {
            regions[((size_t)(t * NB + b)) * CAP + g] = rec;
        } else {
            unsigned sp = atomicAdd(spillCnt, 1u);
            if (sp < SPILLCAP) spill[sp] = make_int4(rec.x, rec.y, rec.z, t);
        }
    }
}

// Fused per-frame kernel: block b = bucket b = nodes [b*128, b*128+128).
// Phase 1: stream sorted run -> LDS acc[128]. Phase 2: quad node update.
__global__ __launch_bounds__(512) void edge_node_kernel(
        const float* __restrict__ x0T, const float* __restrict__ x1T,
        const int4* __restrict__ regions, const unsigned* __restrict__ gcnt,
        const int4* __restrict__ spill, const unsigned* __restrict__ spillCnt,
        const float* __restrict__ m1w1, const float* __restrict__ m1b1,
        const float* __restrict__ m1w2, const float* __restrict__ m1b2,
        const float* __restrict__ m1w3, const float* __restrict__ m1b3,
        const float* __restrict__ m2w1, const float* __restrict__ m2b1,
        const float* __restrict__ m2w2, const float* __restrict__ m2b2,
        const float* __restrict__ ow1, const float* __restrict__ ob1,
        const float* __restrict__ ow2, const float* __restrict__ ob2,
        float* __restrict__ hidden, float* __restrict__ msg_base,
        float* __restrict__ out, int t) {
    __shared__ float acc_s[BN];
    const int b = blockIdx.x, tid = threadIdx.x;
    if (tid < BN) acc_s[tid] = 0.0f;
    __syncthreads();

    // Phase 1: edge aggregation for this bucket
    {
        unsigned cnt = gcnt[t * NB + b];
        if (cnt > CAP) cnt = CAP;
        const int4* p = regions + ((size_t)(t * NB + b)) * CAP;
        for (unsigned i = tid; i < cnt; i += 512) {
            int4 rec = p[i];
            atomicAdd(&acc_s[rec.y & (BN - 1)], msg_base[rec.x] * __int_as_float(rec.z));
        }
        unsigned sp = spillCnt[0];
        for (unsigned j = tid; j < sp; j += 512) {
            int4 rec = spill[j];
            if (rec.w == t && ((unsigned)rec.y >> 7) == (unsigned)b)
                atomicAdd(&acc_s[rec.y & (BN - 1)], msg_base[rec.x] * __int_as_float(rec.z));
        }
    }
    __syncthreads();

    // Phase 2: node update (quad-parallel)
    const int n = b * BN + (tid >> 2);
    const int q = tid & 3;
    if (n >= NN) return;

    const float a = acc_s[tid >> 2];
    const float x1 = x1T[t * NN + n];

    float2 hme = *reinterpret_cast<const float2*>(hidden + (size_t)n * 8 + q * 2);
    float hid[8];
    hid[0] = hme.x; hid[1] = hme.y;
    hid[2] = __shfl_xor(hid[0], 1); hid[3] = __shfl_xor(hid[1], 1);
    hid[4] = __shfl_xor(hid[0], 2); hid[5] = __shfl_xor(hid[1], 2);
    hid[6] = __shfl_xor(hid[2], 2); hid[7] = __shfl_xor(hid[3], 2);

    float acc[8];
    {
        float4 bA = ld4_(m2b1 + q * 8), bB = ld4_(m2b1 + q * 8 + 4);
        acc[0] = bA.x; acc[1] = bA.y; acc[2] = bA.z; acc[3] = bA.w;
        acc[4] = bB.x; acc[5] = bB.y; acc[6] = bB.z; acc[7] = bB.w;
    }
    fma_row8(acc, m2w1 + q * 8, x1);
#pragma unroll
    for (int g = 0; g < 4; ++g) {
        int rq = (q ^ g) * 2;
        fma_row8(acc, m2w1 + (size_t)(1 + rq) * 32 + q * 8, hid[g * 2 + 0]);
        fma_row8(acc, m2w1 + (size_t)(2 + rq) * 32 + q * 8, hid[g * 2 + 1]);
    }
    fma_row8(acc, m2w1 + (size_t)9 * 32 + q * 8, a);
    float u1[8];
#pragma unroll
    for (int jj = 0; jj < 8; ++jj) u1[jj] = reluf_(acc[jj]);

    float pk[8];
#pragma unroll
    for (int k = 0; k < 8; ++k) pk[k] = 0.0f;
#pragma unroll
    for (int jj = 0; jj < 8; ++jj)
        fma_row8(pk, m2w2 + (size_t)(q * 8 + jj) * 8, u1[jj]);
#pragma unroll
    for (int k = 0; k < 8; ++k) {
        pk[k] += __shfl_xor(pk[k], 1);
        pk[k] += __shfl_xor(pk[k], 2);
    }
    float hn[8];
    {
        float4 b2A = ld4_(m2b2), b2B = ld4_(m2b2 + 4);
        hn[0] = tanhf(reluf_(pk[0] + b2A.x));
        hn[1] = tanhf(reluf_(pk[1] + b2A.y));
        hn[2] = tanhf(reluf_(pk[2] + b2A.z));
        hn[3] = tanhf(reluf_(pk[3] + b2A.w));
        hn[4] = tanhf(reluf_(pk[4] + b2B.x));
        hn[5] = tanhf(reluf_(pk[5] + b2B.y));
        hn[6] = tanhf(reluf_(pk[6] + b2B.z));
        hn[7] = tanhf(reluf_(pk[7] + b2B.w));
    }
    if (q == 0) {
        *reinterpret_cast<float4*>(hidden + (size_t)n * 8)     = make_float4(hn[0], hn[1], hn[2], hn[3]);
        *reinterpret_cast<float4*>(hidden + (size_t)n * 8 + 4) = make_float4(hn[4], hn[5], hn[6], hn[7]);
    }

    float o1v[4];
    {
        float4 ob = ld4_(ob1 + q * 4);
        o1v[0] = ob.x; o1v[1] = ob.y; o1v[2] = ob.z; o1v[3] = ob.w;
    }
#pragma unroll
    for (int k = 0; k < 8; ++k) {
        float4 wv = ld4_(ow1 + k * 16 + q * 4);
        o1v[0] += hn[k] * wv.x; o1v[1] += hn[k] * wv.y;
        o1v[2] += hn[k] * wv.z; o1v[3] += hn[k] * wv.w;
    }
    {
        float4 w2v = ld4_(ow2 + q * 4);
        float oop = reluf_(o1v[0]) * w2v.x + reluf_(o1v[1]) * w2v.y +
                    reluf_(o1v[2]) * w2v.z + reluf_(o1v[3]) * w2v.w;
        oop += __shfl_xor(oop, 1);
        oop += __shfl_xor(oop, 2);
        if (q == 0) out[t * NN + n] = sigmoidf_(oop + ob2[0]);
    }

    if (t < TT - 1) {
        float feat0 = x0T[(t + 1) * NN + n];
        float h1[8];
        {
            float4 bA = ld4_(m1b1 + q * 8), bB = ld4_(m1b1 + q * 8 + 4);
            h1[0] = bA.x; h1[1] = bA.y; h1[2] = bA.z; h1[3] = bA.w;
            h1[4] = bB.x; h1[5] = bB.y; h1[6] = bB.z; h1[7] = bB.w;
        }
        fma_row8(h1, m1w1 + q * 8, feat0);
#pragma unroll
        for (int k = 0; k < 8; ++k)
            fma_row8(h1, m1w1 + (size_t)(1 + k) * 32 + q * 8, hn[k]);
#pragma unroll
        for (int jj = 0; jj < 8; ++jj) h1[jj] = reluf_(h1[jj]);

        float h1x[32];
#pragma unroll
        for (int jj = 0; jj < 8; ++jj) h1x[jj] = h1[jj];
#pragma unroll
        for (int jj = 0; jj < 8; ++jj) h1x[8 + jj]  = __shfl_xor(h1x[jj], 1);
#pragma unroll
        for (int jj = 0; jj < 8; ++jj) h1x[16 + jj] = __shfl_xor(h1x[jj], 2);
#pragma unroll
        for (int jj = 0; jj < 8; ++jj) h1x[24 + jj] = __shfl_xor(h1x[8 + jj], 2);

        float acc8[8];
        {
            float4 bA = ld4_(m1b2 + q * 8), bB = ld4_(m1b2 + q * 8 + 4);
            acc8[0] = bA.x; acc8[1] = bA.y; acc8[2] = bA.z; acc8[3] = bA.w;
            acc8[4] = bB.x; acc8[5] = bB.y; acc8[6] = bB.z; acc8[7] = bB.w;
        }
#pragma unroll
        for (int g = 0; g < 4; ++g) {
            int rb = (q ^ g) * 8;
#pragma unroll
            for (int jj = 0; jj < 8; ++jj)
                fma_row8(acc8, m1w2 + (size_t)(rb + jj) * 32 + q * 8, h1x[g * 8 + jj]);
        }
        float s3;
        {
            float4 w3a = ld4_(m1w3 + q * 8), w3b = ld4_(m1w3 + q * 8 + 4);
            s3 = reluf_(acc8[0]) * w3a.x + reluf_(acc8[1]) * w3a.y +
                 reluf_(acc8[2]) * w3a.z + reluf_(acc8[3]) * w3a.w +
                 reluf_(acc8[4]) * w3b.x + reluf_(acc8[5]) * w3b.y +
                 reluf_(acc8[6]) * w3b.z + reluf_(acc8[7]) * w3b.w;
        }
        s3 += __shfl_xor(s3, 1);
        s3 += __shfl_xor(s3, 2);
        if (q == 0) msg_base[n] = sigmoidf_(s3 + m1b3[0]);
    }
}

// ---------------- Legacy fallback (tiny workspace) ----------------
__global__ void edge_kernel(const int* __restrict__ ei, const float* __restrict__ ea,
                            const float* __restrict__ msg_base, float* __restrict__ agg,
                            int t) {
    int g = blockIdx.x * blockDim.x + threadIdx.x;
    int e0 = g * 2;
    if (e0 >= EE) return;
    const int2 s = *reinterpret_cast<const int2*>(ei + (size_t)t * EE + e0);
    const int2 d = *reinterpret_cast<const int2*>(ei + (size_t)(TT + t) * EE + e0);
    atomicAdd(&agg[d.x], msg_base[s.x] * ea[(size_t)e0 * TT + t]);
    atomicAdd(&agg[d.y], msg_base[s.y] * ea[(size_t)(e0 + 1) * TT + t]);
}

__global__ __launch_bounds__(256) void node4_legacy_kernel(
        const float* __restrict__ x,
        const float* __restrict__ m1w1, const float* __restrict__ m1b1,
        const float* __restrict__ m1w2, const float* __restrict__ m1b2,
        const float* __restrict__ m1w3, const float* __restrict__ m1b3,
        const float* __restrict__ m2w1, const float* __restrict__ m2b1,
        const float* __restrict__ m2w2, const float* __restrict__ m2b2,
        const float* __restrict__ ow1, const float* __restrict__ ob1,
        const float* __restrict__ ow2, const float* __restrict__ ob2,
        float* __restrict__ hidden, float* __restrict__ msg_base,
        float* __restrict__ agg, float* __restrict__ out, int t) {
    const int gid = blockIdx.x * 256 + threadIdx.x;
    const int n = gid >> 2;
    const int q = gid & 3;
    if (n >= NN) return;
    const float a = agg[n];
    const float x1 = x[(size_t)n * TT * 2 + t * 2 + 1];
    float2 hme = *reinterpret_cast<const float2*>(hidden + (size_t)n * 8 + q * 2);
    float hid[8];
    hid[0] = hme.x; hid[1] = hme.y;
    hid[2] = __shfl_xor(hid[0], 1); hid[3] = __shfl_xor(hid[1], 1);
    hid[4] = __shfl_xor(hid[0], 2); hid[5] = __shfl_xor(hid[1], 2);
    hid[6] = __shfl_xor(hid[2], 2); hid[7] = __shfl_xor(hid[3], 2);
    float acc[8];
    {
        float4 bA = ld4_(m2b1 + q * 8), bB = ld4_(m2b1 + q * 8 + 4);
        acc[0] = bA.x; acc[1] = bA.y; acc[2] = bA.z; acc[3] = bA.w;
        acc[4] = bB.x; acc[5] = bB.y; acc[6] = bB.z; acc[7] = bB.w;
    }
    fma_row8(acc, m2w1 + q * 8, x1);
#pragma unroll
    for (int g = 0; g < 4; ++g) {
        int rq = (q ^ g) * 2;
        fma_row8(acc, m2w1 + (size_t)(1 + rq) * 32 + q * 8, hid[g * 2 + 0]);
        fma_row8(acc, m2w1 + (size_t)(2 + rq) * 32 + q * 8, hid[g * 2 + 1]);
    }
    fma_row8(acc, m2w1 + (size_t)9 * 32 + q * 8, a);
    float u1[8];
#pragma unroll
    for (int jj = 0; jj < 8; ++jj) u1[jj] = reluf_(acc[jj]);
    float pk[8];
#pragma unroll
    for (int k = 0; k < 8; ++k) pk[k] = 0.0f;
#pragma unroll
    for (int jj = 0; jj < 8; ++jj)
        fma_row8(pk, m2w2 + (size_t)(q * 8 + jj) * 8, u1[jj]);
#pragma unroll
    for (int k = 0; k < 8; ++k) {
        pk[k] += __shfl_xor(pk[k], 1);
        pk[k] += __shfl_xor(pk[k], 2);
    }
    float hn[8];
    {
        float4 b2A = ld4_(m2b2), b2B = ld4_(m2b2 + 4);
        hn[0] = tanhf(reluf_(pk[0] + b2A.x));
        hn[1] = tanhf(reluf_(pk[1] + b2A.y));
        hn[2] = tanhf(reluf_(pk[2] + b2A.z));
        hn[3] = tanhf(reluf_(pk[3] + b2A.w));
        hn[4] = tanhf(reluf_(pk[4] + b2B.x));
        hn[5] = tanhf(reluf_(pk[5] + b2B.y));
        hn[6] = tanhf(reluf_(pk[6] + b2B.z));
        hn[7] = tanhf(reluf_(pk[7] + b2B.w));
    }
    if (q == 0) {
        *reinterpret_cast<float4*>(hidden + (size_t)n * 8)     = make_float4(hn[0], hn[1], hn[2], hn[3]);
        *reinterpret_cast<float4*>(hidden + (size_t)n * 8 + 4) = make_float4(hn[4], hn[5], hn[6], hn[7]);
    }
    float o1v[4];
    {
        float4 ob = ld4_(ob1 + q * 4);
        o1v[0] = ob.x; o1v[1] = ob.y; o1v[2] = ob.z; o1v[3] = ob.w;
    }
#pragma unroll
    for (int k = 0; k < 8; ++k) {
        float4 wv = ld4_(ow1 + k * 16 + q * 4);
        o1v[0] += hn[k] * wv.x; o1v[1] += hn[k] * wv.y;
        o1v[2] += hn[k] * wv.z; o1v[3] += hn[k] * wv.w;
    }
    {
        float4 w2v = ld4_(ow2 + q * 4);
        float oop = reluf_(o1v[0]) * w2v.x + reluf_(o1v[1]) * w2v.y +
                    reluf_(o1v[2]) * w2v.z + reluf_(o1v[3]) * w2v.w;
        oop += __shfl_xor(oop, 1);
        oop += __shfl_xor(oop, 2);
        if (q == 0) out[t * NN + n] = sigmoidf_(oop + ob2[0]);
    }
    if (t < TT - 1) {
        float feat0 = x[(size_t)n * TT * 2 + (t + 1) * 2];
        float h1[8];
        {
            float4 bA = ld4_(m1b1 + q * 8), bB = ld4_(m1b1 + q * 8 + 4);
            h1[0] = bA.x; h1[1] = bA.y; h1[2] = bA.z; h1[3] = bA.w;
            h1[4] = bB.x; h1[5] = bB.y; h1[6] = bB.z; h1[7] = bB.w;
        }
        fma_row8(h1, m1w1 + q * 8, feat0);
#pragma unroll
        for (int k = 0; k < 8; ++k)
            fma_row8(h1, m1w1 + (size_t)(1 + k) * 32 + q * 8, hn[k]);
#pragma unroll
        for (int jj = 0; jj < 8; ++jj) h1[jj] = reluf_(h1[jj]);
        float h1x[32];
#pragma unroll
        for (int jj = 0; jj < 8; ++jj) h1x[jj] = h1[jj];
#pragma unroll
        for (int jj = 0; jj < 8; ++jj) h1x[8 + jj]  = __shfl_xor(h1x[jj], 1);
#pragma unroll
        for (int jj = 0; jj < 8; ++jj) h1x[16 + jj] = __shfl_xor(h1x[jj], 2);
#pragma unroll
        for (int jj = 0; jj < 8; ++jj) h1x[24 + jj] = __shfl_xor(h1x[8 + jj], 2);
        float acc8[8];
        {
            float4 bA = ld4_(m1b2 + q * 8), bB = ld4_(m1b2 + q * 8 + 4);
            acc8[0] = bA.x; acc8[1] = bA.y; acc8[2] = bA.z; acc8[3] = bA.w;
            acc8[4] = bB.x; acc8[5] = bB.y; acc8[6] = bB.z; acc8[7] = bB.w;
        }
#pragma unroll
        for (int g = 0; g < 4; ++g) {
            int rb = (q ^ g) * 8;
#pragma unroll
            for (int jj = 0; jj < 8; ++jj)
                fma_row8(acc8, m1w2 + (size_t)(rb + jj) * 32 + q * 8, h1x[g * 8 + jj]);
        }
        float s3;
        {
            float4 w3a = ld4_(m1w3 + q * 8), w3b = ld4_(m1w3 + q * 8 + 4);
            s3 = reluf_(acc8[0]) * w3a.x + reluf_(acc8[1]) * w3a.y +
                 reluf_(acc8[2]) * w3a.z + reluf_(acc8[3]) * w3a.w +
                 reluf_(acc8[4]) * w3b.x + reluf_(acc8[5]) * w3b.y +
                 reluf_(acc8[6]) * w3b.z + reluf_(acc8[7]) * w3b.w;
        }
        s3 += __shfl_xor(s3, 1);
        s3 += __shfl_xor(s3, 2);
        if (q == 0) {
            msg_base[n] = sigmoidf_(s3 + m1b3[0]);
            agg[n] = 0.0f;
        }
    }
}

extern "C" void kernel_launch(void* const* d_in, const int* in_sizes, int n_in,
                              void* d_out, int out_size, void* d_ws, size_t ws_size,
                              hipStream_t stream) {
    (void)in_sizes; (void)n_in; (void)out_size;
    const float* x    = (const float*)d_in[0];
    const int*   ei   = (const int*)d_in[1];
    const float* ea   = (const float*)d_in[2];
    const float* m1w1 = (const float*)d_in[3];
    const float* m1b1 = (const float*)d_in[4];
    const float* m1w2 = (const float*)d_in[5];
    const float* m1b2 = (const float*)d_in[6];
    const float* m1w3 = (const float*)d_in[7];
    const float* m1b3 = (const float*)d_in[8];
    const float* m2w1 = (const float*)d_in[9];
    const float* m2b1 = (const float*)d_in[10];
    const float* m2w2 = (const float*)d_in[11];
    const float* m2b2 = (const float*)d_in[12];
    const float* ow1  = (const float*)d_in[13];
    const float* ob1  = (const float*)d_in[14];
    const float* ow2  = (const float*)d_in[15];
    const float* ob2  = (const float*)d_in[16];
    float* out = (float*)d_out;

    // Workspace carve (16B-aligned)
    char* wp = (char*)d_ws;
    float* hidden   = (float*)wp; wp += (size_t)NN * 8 * 4;
    float* msg_base = (float*)wp; wp += (size_t)NN * 4;
    float* agg      = (float*)wp; wp += (size_t)NN * 4;
    float* x0T      = (float*)wp; wp += (size_t)NN * TT * 4;
    float* x1T      = (float*)wp; wp += (size_t)NN * TT * 4;
    int4*  regions  = (int4*)wp;  wp += (size_t)NB * TT * CAP * 16;  // 192 MB
    int4*  spill    = (int4*)wp;  wp += (size_t)SPILLCAP * 16;
    unsigned* gcnt    = (unsigned*)wp; wp += (size_t)NB * TT * 4;
    unsigned* spillCnt = (unsigned*)wp; wp += 64;
    size_t need = (size_t)(wp - (char*)d_ws);

    int sorted = (ws_size >= need) ? 1 : 0;

    dim3 blk(256);
    int nodeBlocks = (NN + 255) / 256;
    int edgeBlocksLegacy = (EE / 2 + 255) / 256;
    int node4BlocksLegacy = (NN * 4 + 255) / 256;

    pre_kernel<<<nodeBlocks, blk, 0, stream>>>(x, m1w1, m1b1, m1w2, m1b2, m1w3, m1b3,
                                               hidden, msg_base, agg, x0T, x1T,
                                               gcnt, spillCnt, sorted);
    if (sorted) {
        reorder_kernel<<<dim3(TT, NCHUNK), blk, 0, stream>>>(ei, ea, gcnt, regions,
                                                             spill, spillCnt);
        for (int t = 0; t < TT; ++t) {
            edge_node_kernel<<<NB, dim3(512), 0, stream>>>(
                x0T, x1T, regions, gcnt, spill, spillCnt,
                m1w1, m1b1, m1w2, m1b2, m1w3, m1b3,
                m2w1, m2b1, m2w2, m2b2,
                ow1, ob1, ow2, ob2,
                hidden, msg_base, out, t);
        }
    } else {
        for (int t = 0; t < TT; ++t) {
            edge_kernel<<<edgeBlocksLegacy, blk, 0, stream>>>(ei, ea, msg_base, agg, t);
            node4_legacy_kernel<<<node4BlocksLegacy, blk, 0, stream>>>(
                x, m1w1, m1b1, m1w2, m1b2, m1w3, m1b3,
                m2w1, m2b1, m2w2, m2b2,
                ow1, ob1, ow2, ob2,
                hidden, msg_base, agg, out, t);
        }
    }
}

// Round 9
// 485.689 us; speedup vs baseline: 1.4784x; 1.2228x over previous
//
#include <hip/hip_runtime.h>

#define NN 50000
#define TT 10
#define EE 1000000

#define NB 391         // dst buckets; bucket = dst >> 7
#define BN 128         // nodes per bucket
#define NBP 512        // padded bucket slots for block scan
#define CAP 3072       // region slots per (t,bucket); mean 2558, sigma ~50
#define CHUNK 2048
#define NCHUNK 489     // ceil(EE/CHUNK)
#define KPT (CHUNK / 256)
#define SPILLCAP 8192

// LDS weight layout (float offsets, all 4-aligned)
#define OFF_M2W1 0
#define OFF_M2B1 320
#define OFF_M2W2 352
#define OFF_M2B2 608
#define OFF_OW1  616
#define OFF_OB1  744
#define OFF_OW2  760
#define OFF_M1W1 776
#define OFF_M1B1 1064
#define OFF_M1W2 1096
#define OFF_M1B2 2120
#define OFF_M1W3 2152
#define OFF_OB2  2184
#define OFF_M1B3 2185
#define WTOT     2188

__device__ __forceinline__ float sigmoidf_(float v) { return 1.0f / (1.0f + __expf(-v)); }
__device__ __forceinline__ float reluf_(float v) { return v > 0.0f ? v : 0.0f; }

__device__ __forceinline__ float4 ld4_(const float* __restrict__ p) {
    return *reinterpret_cast<const float4*>(p);
}
__device__ __forceinline__ void fma_row8(float* acc, const float* w, float f) {
    float4 a = *reinterpret_cast<const float4*>(w);
    float4 b = *reinterpret_cast<const float4*>(w + 4);
    acc[0] += f * a.x; acc[1] += f * a.y; acc[2] += f * a.z; acc[3] += f * a.w;
    acc[4] += f * b.x; acc[5] += f * b.y; acc[6] += f * b.z; acc[7] += f * b.w;
}

// Cheap MLP1 for frame 0 (hidden = 0 -> layer1 has only row 0 active).
__device__ __forceinline__ float mlp1_frame0(float x00,
                                             const float* __restrict__ w1,
                                             const float* __restrict__ b1,
                                             const float* __restrict__ w2,
                                             const float* __restrict__ b2,
                                             const float* __restrict__ w3,
                                             const float* __restrict__ b3) {
    float h1[32];
#pragma unroll
    for (int j = 0; j < 32; ++j) h1[j] = reluf_(b1[j] + x00 * w1[j]);
    float h2[32];
#pragma unroll
    for (int j = 0; j < 32; ++j) h2[j] = b2[j];
#pragma unroll
    for (int i = 0; i < 32; ++i) {
        float f = h1[i];
#pragma unroll
        for (int j = 0; j < 32; ++j) h2[j] += f * w2[i * 32 + j];
    }
    float acc = b3[0];
#pragma unroll
    for (int j = 0; j < 32; ++j) acc += reluf_(h2[j]) * w3[j];
    return sigmoidf_(acc);
}

// Pre-pass. Sorted: grid covers EE (eaT transpose) + NN work + gcnt/spill zero.
__global__ void pre_kernel(const float* __restrict__ x,
                           const float* __restrict__ ea,
                           const float* __restrict__ w1, const float* __restrict__ b1,
                           const float* __restrict__ w2, const float* __restrict__ b2,
                           const float* __restrict__ w3, const float* __restrict__ b3,
                           float* __restrict__ hidden, float* __restrict__ msgA,
                           float* __restrict__ agg,
                           float* __restrict__ x0T, float* __restrict__ x1T,
                           float* __restrict__ eaT,
                           unsigned* __restrict__ gcnt, unsigned* __restrict__ spillCnt,
                           int sorted) {
    int g = blockIdx.x * blockDim.x + threadIdx.x;
    if (sorted) {
        if (g < EE) {
            const float2* row = reinterpret_cast<const float2*>(ea + (size_t)g * TT);
            float v[TT];
#pragma unroll
            for (int c = 0; c < 5; ++c) { float2 p = row[c]; v[2 * c] = p.x; v[2 * c + 1] = p.y; }
#pragma unroll
            for (int tt = 0; tt < TT; ++tt) eaT[(size_t)tt * EE + g] = v[tt];
        }
        if (g < NB * TT) gcnt[g] = 0u;
        if (g == 0) spillCnt[0] = 0u;
    }
    if (g >= NN) return;
    float x00;
    if (sorted) {
        const float2* xr = reinterpret_cast<const float2*>(x + (size_t)g * TT * 2);
        float x0v[TT], x1v[TT];
#pragma unroll
        for (int tt = 0; tt < TT; ++tt) { float2 p = xr[tt]; x0v[tt] = p.x; x1v[tt] = p.y; }
#pragma unroll
        for (int tt = 0; tt < TT; ++tt) { x0T[tt * NN + g] = x0v[tt]; x1T[tt * NN + g] = x1v[tt]; }
        x00 = x0v[0];
    } else {
        x00 = x[(size_t)g * TT * 2];
    }
    agg[g] = 0.0f;
    msgA[g] = mlp1_frame0(x00, w1, b1, w2, b2, w3, b3);
#pragma unroll
    for (int k = 0; k < 8; ++k) hidden[g * 8 + k] = 0.0f;
}

// One-time reorder: grid (t, chunk). LDS hist -> block scan -> global atomic
// region alloc -> LDS-staged compaction -> packed 8B records (src|dstl<<17, ea).
__global__ __launch_bounds__(256) void reorder_kernel(const int* __restrict__ ei,
                                                      const float* __restrict__ eaT,
                                                      unsigned* __restrict__ gcnt,
                                                      int2* __restrict__ regions,
                                                      int4* __restrict__ spill,
                                                      unsigned* __restrict__ spillCnt) {
    __shared__ int4 stg[CHUNK];
    __shared__ unsigned h4[4][NBP];
    __shared__ unsigned lbase[NBP], cur[NBP], gbase[NBP];
    __shared__ unsigned bscan[256];
    __shared__ unsigned cnt_s;
    const int t = blockIdx.x, c = blockIdx.y;
    const int tid = threadIdx.x, w = tid >> 6;

    for (int i = tid; i < 4 * NBP; i += 256) (&h4[0][0])[i] = 0u;
    __syncthreads();

    const int* srcp = ei + (size_t)t * EE;
    const int* dstp = ei + (size_t)(TT + t) * EE;
    int se[KPT], de[KPT];
    float ev[KPT];
#pragma unroll
    for (int k = 0; k < KPT; ++k) {
        int e = c * CHUNK + k * 256 + tid;
        if (e < EE) {
            se[k] = srcp[e];
            de[k] = dstp[e];
            ev[k] = eaT[(size_t)t * EE + e];   // coalesced
            atomicAdd(&h4[w][(unsigned)de[k] >> 7], 1u);
        } else {
            de[k] = -1; se[k] = 0; ev[k] = 0.0f;
        }
    }
    __syncthreads();

    unsigned c0 = h4[0][2 * tid] + h4[1][2 * tid] + h4[2][2 * tid] + h4[3][2 * tid];
    unsigned c1 = h4[0][2 * tid + 1] + h4[1][2 * tid + 1] + h4[2][2 * tid + 1] + h4[3][2 * tid + 1];
    unsigned mys = c0 + c1;
    bscan[tid] = mys;
    __syncthreads();
    for (int off = 1; off < 256; off <<= 1) {
        unsigned vv = (tid >= off) ? bscan[tid - off] : 0u;
        __syncthreads();
        bscan[tid] += vv;
        __syncthreads();
    }
    unsigned excl = bscan[tid] - mys;
    lbase[2 * tid] = excl;           cur[2 * tid] = excl;
    lbase[2 * tid + 1] = excl + c0;  cur[2 * tid + 1] = excl + c0;
    if (tid == 255) cnt_s = bscan[255];
    {
        int b0 = 2 * tid, b1 = 2 * tid + 1;
        gbase[b0] = (b0 < NB) ? atomicAdd(&gcnt[t * NB + b0], c0) : 0u;
        gbase[b1] = (b1 < NB) ? atomicAdd(&gcnt[t * NB + b1], c1) : 0u;
    }
    __syncthreads();

#pragma unroll
    for (int k = 0; k < KPT; ++k) {
        if (de[k] >= 0) {
            unsigned b = (unsigned)de[k] >> 7;
            unsigned slot = atomicAdd(&cur[b], 1u);
            stg[slot] = make_int4(se[k], de[k], __float_as_int(ev[k]), 0);
        }
    }
    __syncthreads();

    const unsigned cnt = cnt_s;
    for (unsigned i = tid; i < cnt; i += 256) {
        int4 rec = stg[i];
        unsigned b = (unsigned)rec.y >> 7;
        unsigned g = gbase[b] + (i - lbase[b]);
        if (g < CAP) {
            unsigned u = (unsigned)rec.x | (((unsigned)rec.y & 127u) << 17);
            regions[((size_t)(t * NB + b)) * CAP + g] = make_int2((int)u, rec.z);
        } else {
            unsigned sp = atomicAdd(spillCnt, 1u);
            if (sp < SPILLCAP) spill[sp] = make_int4(rec.x, rec.y, rec.z, t);
        }
    }
}

// Fused per-frame kernel. Block b = bucket b = nodes [b*128, b*128+128).
// Weights staged in LDS. Phase 1: stream 8B records -> LDS acc.
// Phase 2: quad node update; writes msgOut (ping-pong, race-free).
__global__ __launch_bounds__(512) void edge_node_kernel(
        const float* __restrict__ x0T, const float* __restrict__ x1T,
        const int2* __restrict__ regions, const unsigned* __restrict__ gcnt,
        const int4* __restrict__ spill, const unsigned* __restrict__ spillCnt,
        const float* __restrict__ m1w1, const float* __restrict__ m1b1,
        const float* __restrict__ m1w2, const float* __restrict__ m1b2,
        const float* __restrict__ m1w3, const float* __restrict__ m1b3,
        const float* __restrict__ m2w1, const float* __restrict__ m2b1,
        const float* __restrict__ m2w2, const float* __restrict__ m2b2,
        const float* __restrict__ ow1, const float* __restrict__ ob1,
        const float* __restrict__ ow2, const float* __restrict__ ob2,
        float* __restrict__ hidden, const float* __restrict__ msgIn,
        float* __restrict__ msgOut, float* __restrict__ out, int t) {
    __shared__ __align__(16) float wsh[WTOT];
    __shared__ float acc_s[BN];
    const int b = blockIdx.x, tid = threadIdx.x;

    // stage weights to LDS
    for (int i = tid; i < 320; i += 512) wsh[OFF_M2W1 + i] = m2w1[i];
    for (int i = tid; i < 256; i += 512) wsh[OFF_M2W2 + i] = m2w2[i];
    for (int i = tid; i < 288; i += 512) wsh[OFF_M1W1 + i] = m1w1[i];
    for (int i = tid; i < 1024; i += 512) wsh[OFF_M1W2 + i] = m1w2[i];
    if (tid < 32) {
        wsh[OFF_M2B1 + tid] = m2b1[tid];
        wsh[OFF_M1B1 + tid] = m1b1[tid];
        wsh[OFF_M1B2 + tid] = m1b2[tid];
        wsh[OFF_M1W3 + tid] = m1w3[tid];
    }
    if (tid >= 32 && tid < 40) wsh[OFF_M2B2 + tid - 32] = m2b2[tid - 32];
    if (tid >= 64 && tid < 192) wsh[OFF_OW1 + tid - 64] = ow1[tid - 64];
    if (tid >= 192 && tid < 208) wsh[OFF_OB1 + tid - 192] = ob1[tid - 192];
    if (tid >= 208 && tid < 224) wsh[OFF_OW2 + tid - 208] = ow2[tid - 208];
    if (tid == 224) wsh[OFF_OB2] = ob2[0];
    if (tid == 225) wsh[OFF_M1B3] = m1b3[0];
    if (tid < BN) acc_s[tid] = 0.0f;
    __syncthreads();

    // Phase 1: edge aggregation
    {
        unsigned cnt = gcnt[t * NB + b];
        if (cnt > CAP) cnt = CAP;
        const int2* p = regions + ((size_t)(t * NB + b)) * CAP;
        for (unsigned i = tid; i < cnt; i += 512) {
            int2 rec = p[i];
            unsigned u = (unsigned)rec.x;
            atomicAdd(&acc_s[u >> 17], msgIn[u & 0x1FFFFu] * __int_as_float(rec.y));
        }
        unsigned sp = spillCnt[0];
        for (unsigned j = tid; j < sp; j += 512) {
            int4 rec = spill[j];
            if (rec.w == t && ((unsigned)rec.y >> 7) == (unsigned)b)
                atomicAdd(&acc_s[rec.y & (BN - 1)], msgIn[rec.x] * __int_as_float(rec.z));
        }
    }
    __syncthreads();

    // Phase 2: quad node update (weights from LDS)
    const int n = b * BN + (tid >> 2);
    const int q = tid & 3;
    if (n >= NN) return;

    const float a = acc_s[tid >> 2];
    const float x1 = x1T[t * NN + n];

    float2 hme = *reinterpret_cast<const float2*>(hidden + (size_t)n * 8 + q * 2);
    float hid[8];
    hid[0] = hme.x; hid[1] = hme.y;
    hid[2] = __shfl_xor(hid[0], 1); hid[3] = __shfl_xor(hid[1], 1);
    hid[4] = __shfl_xor(hid[0], 2); hid[5] = __shfl_xor(hid[1], 2);
    hid[6] = __shfl_xor(hid[2], 2); hid[7] = __shfl_xor(hid[3], 2);

    float acc[8];
    {
        float4 bA = ld4_(&wsh[OFF_M2B1 + q * 8]), bB = ld4_(&wsh[OFF_M2B1 + q * 8 + 4]);
        acc[0] = bA.x; acc[1] = bA.y; acc[2] = bA.z; acc[3] = bA.w;
        acc[4] = bB.x; acc[5] = bB.y; acc[6] = bB.z; acc[7] = bB.w;
    }
    fma_row8(acc, &wsh[OFF_M2W1 + q * 8], x1);
#pragma unroll
    for (int g = 0; g < 4; ++g) {
        int rq = (q ^ g) * 2;
        fma_row8(acc, &wsh[OFF_M2W1 + (1 + rq) * 32 + q * 8], hid[g * 2 + 0]);
        fma_row8(acc, &wsh[OFF_M2W1 + (2 + rq) * 32 + q * 8], hid[g * 2 + 1]);
    }
    fma_row8(acc, &wsh[OFF_M2W1 + 9 * 32 + q * 8], a);
    float u1[8];
#pragma unroll
    for (int jj = 0; jj < 8; ++jj) u1[jj] = reluf_(acc[jj]);

    float pk[8];
#pragma unroll
    for (int k = 0; k < 8; ++k) pk[k] = 0.0f;
#pragma unroll
    for (int jj = 0; jj < 8; ++jj)
        fma_row8(pk, &wsh[OFF_M2W2 + (q * 8 + jj) * 8], u1[jj]);
#pragma unroll
    for (int k = 0; k < 8; ++k) {
        pk[k] += __shfl_xor(pk[k], 1);
        pk[k] += __shfl_xor(pk[k], 2);
    }
    float hn[8];
    {
        float4 b2A = ld4_(&wsh[OFF_M2B2]), b2B = ld4_(&wsh[OFF_M2B2 + 4]);
        hn[0] = tanhf(reluf_(pk[0] + b2A.x));
        hn[1] = tanhf(reluf_(pk[1] + b2A.y));
        hn[2] = tanhf(reluf_(pk[2] + b2A.z));
        hn[3] = tanhf(reluf_(pk[3] + b2A.w));
        hn[4] = tanhf(reluf_(pk[4] + b2B.x));
        hn[5] = tanhf(reluf_(pk[5] + b2B.y));
        hn[6] = tanhf(reluf_(pk[6] + b2B.z));
        hn[7] = tanhf(reluf_(pk[7] + b2B.w));
    }
    if (q == 0) {
        *reinterpret_cast<float4*>(hidden + (size_t)n * 8)     = make_float4(hn[0], hn[1], hn[2], hn[3]);
        *reinterpret_cast<float4*>(hidden + (size_t)n * 8 + 4) = make_float4(hn[4], hn[5], hn[6], hn[7]);
    }

    float o1v[4];
    {
        float4 ob = ld4_(&wsh[OFF_OB1 + q * 4]);
        o1v[0] = ob.x; o1v[1] = ob.y; o1v[2] = ob.z; o1v[3] = ob.w;
    }
#pragma unroll
    for (int k = 0; k < 8; ++k) {
        float4 wv = ld4_(&wsh[OFF_OW1 + k * 16 + q * 4]);
        o1v[0] += hn[k] * wv.x; o1v[1] += hn[k] * wv.y;
        o1v[2] += hn[k] * wv.z; o1v[3] += hn[k] * wv.w;
    }
    {
        float4 w2v = ld4_(&wsh[OFF_OW2 + q * 4]);
        float oop = reluf_(o1v[0]) * w2v.x + reluf_(o1v[1]) * w2v.y +
                    reluf_(o1v[2]) * w2v.z + reluf_(o1v[3]) * w2v.w;
        oop += __shfl_xor(oop, 1);
        oop += __shfl_xor(oop, 2);
        if (q == 0) out[t * NN + n] = sigmoidf_(oop + wsh[OFF_OB2]);
    }

    if (t < TT - 1) {
        float feat0 = x0T[(t + 1) * NN + n];
        float h1[8];
        {
            float4 bA = ld4_(&wsh[OFF_M1B1 + q * 8]), bB = ld4_(&wsh[OFF_M1B1 + q * 8 + 4]);
            h1[0] = bA.x; h1[1] = bA.y; h1[2] = bA.z; h1[3] = bA.w;
            h1[4] = bB.x; h1[5] = bB.y; h1[6] = bB.z; h1[7] = bB.w;
        }
        fma_row8(h1, &wsh[OFF_M1W1 + q * 8], feat0);
#pragma unroll
        for (int k = 0; k < 8; ++k)
            fma_row8(h1, &wsh[OFF_M1W1 + (1 + k) * 32 + q * 8], hn[k]);
#pragma unroll
        for (int jj = 0; jj < 8; ++jj) h1[jj] = reluf_(h1[jj]);

        float h1x[32];
#pragma unroll
        for (int jj = 0; jj < 8; ++jj) h1x[jj] = h1[jj];
#pragma unroll
        for (int jj = 0; jj < 8; ++jj) h1x[8 + jj]  = __shfl_xor(h1x[jj], 1);
#pragma unroll
        for (int jj = 0; jj < 8; ++jj) h1x[16 + jj] = __shfl_xor(h1x[jj], 2);
#pragma unroll
        for (int jj = 0; jj < 8; ++jj) h1x[24 + jj] = __shfl_xor(h1x[8 + jj], 2);

        float acc8[8];
        {
            float4 bA = ld4_(&wsh[OFF_M1B2 + q * 8]), bB = ld4_(&wsh[OFF_M1B2 + q * 8 + 4]);
            acc8[0] = bA.x; acc8[1] = bA.y; acc8[2] = bA.z; acc8[3] = bA.w;
            acc8[4] = bB.x; acc8[5] = bB.y; acc8[6] = bB.z; acc8[7] = bB.w;
        }
#pragma unroll
        for (int g = 0; g < 4; ++g) {
            int rb = (q ^ g) * 8;
#pragma unroll
            for (int jj = 0; jj < 8; ++jj)
                fma_row8(acc8, &wsh[OFF_M1W2 + (rb + jj) * 32 + q * 8], h1x[g * 8 + jj]);
        }
        float s3;
        {
            float4 w3a = ld4_(&wsh[OFF_M1W3 + q * 8]), w3b = ld4_(&wsh[OFF_M1W3 + q * 8 + 4]);
            s3 = reluf_(acc8[0]) * w3a.x + reluf_(acc8[1]) * w3a.y +
                 reluf_(acc8[2]) * w3a.z + reluf_(acc8[3]) * w3a.w +
                 reluf_(acc8[4]) * w3b.x + reluf_(acc8[5]) * w3b.y +
                 reluf_(acc8[6]) * w3b.z + reluf_(acc8[7]) * w3b.w;
        }
        s3 += __shfl_xor(s3, 1);
        s3 += __shfl_xor(s3, 2);
        if (q == 0) msgOut[n] = sigmoidf_(s3 + wsh[OFF_M1B3]);
    }
}

// ---------------- Legacy fallback (tiny workspace) ----------------
__global__ void edge_kernel(const int* __restrict__ ei, const float* __restrict__ ea,
                            const float* __restrict__ msg_base, float* __restrict__ agg,
                            int t) {
    int g = blockIdx.x * blockDim.x + threadIdx.x;
    int e0 = g * 2;
    if (e0 >= EE) return;
    const int2 s = *reinterpret_cast<const int2*>(ei + (size_t)t * EE + e0);
    const int2 d = *reinterpret_cast<const int2*>(ei + (size_t)(TT + t) * EE + e0);
    atomicAdd(&agg[d.x], msg_base[s.x] * ea[(size_t)e0 * TT + t]);
    atomicAdd(&agg[d.y], msg_base[s.y] * ea[(size_t)(e0 + 1) * TT + t]);
}

__global__ __launch_bounds__(256) void node4_legacy_kernel(
        const float* __restrict__ x,
        const float* __restrict__ m1w1, const float* __restrict__ m1b1,
        const float* __restrict__ m1w2, const float* __restrict__ m1b2,
        const float* __restrict__ m1w3, const float* __restrict__ m1b3,
        const float* __restrict__ m2w1, const float* __restrict__ m2b1,
        const float* __restrict__ m2w2, const float* __restrict__ m2b2,
        const float* __restrict__ ow1, const float* __restrict__ ob1,
        const float* __restrict__ ow2, const float* __restrict__ ob2,
        float* __restrict__ hidden, float* __restrict__ msg_base,
        float* __restrict__ agg, float* __restrict__ out, int t) {
    const int gid = blockIdx.x * 256 + threadIdx.x;
    const int n = gid >> 2;
    const int q = gid & 3;
    if (n >= NN) return;
    const float a = agg[n];
    const float x1 = x[(size_t)n * TT * 2 + t * 2 + 1];
    float2 hme = *reinterpret_cast<const float2*>(hidden + (size_t)n * 8 + q * 2);
    float hid[8];
    hid[0] = hme.x; hid[1] = hme.y;
    hid[2] = __shfl_xor(hid[0], 1); hid[3] = __shfl_xor(hid[1], 1);
    hid[4] = __shfl_xor(hid[0], 2); hid[5] = __shfl_xor(hid[1], 2);
    hid[6] = __shfl_xor(hid[2], 2); hid[7] = __shfl_xor(hid[3], 2);
    float acc[8];
    {
        float4 bA = ld4_(m2b1 + q * 8), bB = ld4_(m2b1 + q * 8 + 4);
        acc[0] = bA.x; acc[1] = bA.y; acc[2] = bA.z; acc[3] = bA.w;
        acc[4] = bB.x; acc[5] = bB.y; acc[6] = bB.z; acc[7] = bB.w;
    }
    fma_row8(acc, m2w1 + q * 8, x1);
#pragma unroll
    for (int g = 0; g < 4; ++g) {
        int rq = (q ^ g) * 2;
        fma_row8(acc, m2w1 + (size_t)(1 + rq) * 32 + q * 8, hid[g * 2 + 0]);
        fma_row8(acc, m2w1 + (size_t)(2 + rq) * 32 + q * 8, hid[g * 2 + 1]);
    }
    fma_row8(acc, m2w1 + (size_t)9 * 32 + q * 8, a);
    float u1[8];
#pragma unroll
    for (int jj = 0; jj < 8; ++jj) u1[jj] = reluf_(acc[jj]);
    float pk[8];
#pragma unroll
    for (int k = 0; k < 8; ++k) pk[k] = 0.0f;
#pragma unroll
    for (int jj = 0; jj < 8; ++jj)
        fma_row8(pk, m2w2 + (size_t)(q * 8 + jj) * 8, u1[jj]);
#pragma unroll
    for (int k = 0; k < 8; ++k) {
        pk[k] += __shfl_xor(pk[k], 1);
        pk[k] += __shfl_xor(pk[k], 2);
    }
    float hn[8];
    {
        float4 b2A = ld4_(m2b2), b2B = ld4_(m2b2 + 4);
        hn[0] = tanhf(reluf_(pk[0] + b2A.x));
        hn[1] = tanhf(reluf_(pk[1] + b2A.y));
        hn[2] = tanhf(reluf_(pk[2] + b2A.z));
        hn[3] = tanhf(reluf_(pk[3] + b2A.w));
        hn[4] = tanhf(reluf_(pk[4] + b2B.x));
        hn[5] = tanhf(reluf_(pk[5] + b2B.y));
        hn[6] = tanhf(reluf_(pk[6] + b2B.z));
        hn[7] = tanhf(reluf_(pk[7] + b2B.w));
    }
    if (q == 0) {
        *reinterpret_cast<float4*>(hidden + (size_t)n * 8)     = make_float4(hn[0], hn[1], hn[2], hn[3]);
        *reinterpret_cast<float4*>(hidden + (size_t)n * 8 + 4) = make_float4(hn[4], hn[5], hn[6], hn[7]);
    }
    float o1v[4];
    {
        float4 ob = ld4_(ob1 + q * 4);
        o1v[0] = ob.x; o1v[1] = ob.y; o1v[2] = ob.z; o1v[3] = ob.w;
    }
#pragma unroll
    for (int k = 0; k < 8; ++k) {
        float4 wv = ld4_(ow1 + k * 16 + q * 4);
        o1v[0] += hn[k] * wv.x; o1v[1] += hn[k] * wv.y;
        o1v[2] += hn[k] * wv.z; o1v[3] += hn[k] * wv.w;
    }
    {
        float4 w2v = ld4_(ow2 + q * 4);
        float oop = reluf_(o1v[0]) * w2v.x + reluf_(o1v[1]) * w2v.y +
                    reluf_(o1v[2]) * w2v.z + reluf_(o1v[3]) * w2v.w;
        oop += __shfl_xor(oop, 1);
        oop += __shfl_xor(oop, 2);
        if (q == 0) out[t * NN + n] = sigmoidf_(oop + ob2[0]);
    }
    if (t < TT - 1) {
        float feat0 = x[(size_t)n * TT * 2 + (t + 1) * 2];
        float h1[8];
        {
            float4 bA = ld4_(m1b1 + q * 8), bB = ld4_(m1b1 + q * 8 + 4);
            h1[0] = bA.x; h1[1] = bA.y; h1[2] = bA.z; h1[3] = bA.w;
            h1[4] = bB.x; h1[5] = bB.y; h1[6] = bB.z; h1[7] = bB.w;
        }
        fma_row8(h1, m1w1 + q * 8, feat0);
#pragma unroll
        for (int k = 0; k < 8; ++k)
            fma_row8(h1, m1w1 + (size_t)(1 + k) * 32 + q * 8, hn[k]);
#pragma unroll
        for (int jj = 0; jj < 8; ++jj) h1[jj] = reluf_(h1[jj]);
        float h1x[32];
#pragma unroll
        for (int jj = 0; jj < 8; ++jj) h1x[jj] = h1[jj];
#pragma unroll
        for (int jj = 0; jj < 8; ++jj) h1x[8 + jj]  = __shfl_xor(h1x[jj], 1);
#pragma unroll
        for (int jj = 0; jj < 8; ++jj) h1x[16 + jj] = __shfl_xor(h1x[jj], 2);
#pragma unroll
        for (int jj = 0; jj < 8; ++jj) h1x[24 + jj] = __shfl_xor(h1x[8 + jj], 2);
        float acc8[8];
        {
            float4 bA = ld4_(m1b2 + q * 8), bB = ld4_(m1b2 + q * 8 + 4);
            acc8[0] = bA.x; acc8[1] = bA.y; acc8[2] = bA.z; acc8[3] = bA.w;
            acc8[4] = bB.x; acc8[5] = bB.y; acc8[6] = bB.z; acc8[7] = bB.w;
        }
#pragma unroll
        for (int g = 0; g < 4; ++g) {
            int rb = (q ^ g) * 8;
#pragma unroll
            for (int jj = 0; jj < 8; ++jj)
                fma_row8(acc8, m1w2 + (size_t)(rb + jj) * 32 + q * 8, h1x[g * 8 + jj]);
        }
        float s3;
        {
            float4 w3a = ld4_(m1w3 + q * 8), w3b = ld4_(m1w3 + q * 8 + 4);
            s3 = reluf_(acc8[0]) * w3a.x + reluf_(acc8[1]) * w3a.y +
                 reluf_(acc8[2]) * w3a.z + reluf_(acc8[3]) * w3a.w +
                 reluf_(acc8[4]) * w3b.x + reluf_(acc8[5]) * w3b.y +
                 reluf_(acc8[6]) * w3b.z + reluf_(acc8[7]) * w3b.w;
        }
        s3 += __shfl_xor(s3, 1);
        s3 += __shfl_xor(s3, 2);
        if (q == 0) {
            msg_base[n] = sigmoidf_(s3 + m1b3[0]);
            agg[n] = 0.0f;
        }
    }
}

extern "C" void kernel_launch(void* const* d_in, const int* in_sizes, int n_in,
                              void* d_out, int out_size, void* d_ws, size_t ws_size,
                              hipStream_t stream) {
    (void)in_sizes; (void)n_in; (void)out_size;
    const float* x    = (const float*)d_in[0];
    const int*   ei   = (const int*)d_in[1];
    const float* ea   = (const float*)d_in[2];
    const float* m1w1 = (const float*)d_in[3];
    const float* m1b1 = (const float*)d_in[4];
    const float* m1w2 = (const float*)d_in[5];
    const float* m1b2 = (const float*)d_in[6];
    const float* m1w3 = (const float*)d_in[7];
    const float* m1b3 = (const float*)d_in[8];
    const float* m2w1 = (const float*)d_in[9];
    const float* m2b1 = (const float*)d_in[10];
    const float* m2w2 = (const float*)d_in[11];
    const float* m2b2 = (const float*)d_in[12];
    const float* ow1  = (const float*)d_in[13];
    const float* ob1  = (const float*)d_in[14];
    const float* ow2  = (const float*)d_in[15];
    const float* ob2  = (const float*)d_in[16];
    float* out = (float*)d_out;

    // Workspace carve (16B-aligned)
    char* wp = (char*)d_ws;
    float* hidden   = (float*)wp; wp += (size_t)NN * 8 * 4;
    float* msgA     = (float*)wp; wp += (size_t)NN * 4;
    float* msgB     = (float*)wp; wp += (size_t)NN * 4;
    float* agg      = (float*)wp; wp += (size_t)NN * 4;
    float* x0T      = (float*)wp; wp += (size_t)NN * TT * 4;
    float* x1T      = (float*)wp; wp += (size_t)NN * TT * 4;
    float* eaT      = (float*)wp; wp += (size_t)TT * EE * 4;        // 40 MB
    int2*  regions  = (int2*)wp;  wp += (size_t)NB * TT * CAP * 8;  // 96 MB
    int4*  spill    = (int4*)wp;  wp += (size_t)SPILLCAP * 16;
    unsigned* gcnt    = (unsigned*)wp; wp += (size_t)NB * TT * 4;
    unsigned* spillCnt = (unsigned*)wp; wp += 64;
    size_t need = (size_t)(wp - (char*)d_ws);

    int sorted = (ws_size >= need) ? 1 : 0;

    dim3 blk(256);
    int nodeBlocks = (NN + 255) / 256;
    int preBlocks = sorted ? (EE + 255) / 256 : nodeBlocks;
    int edgeBlocksLegacy = (EE / 2 + 255) / 256;
    int node4BlocksLegacy = (NN * 4 + 255) / 256;

    pre_kernel<<<preBlocks, blk, 0, stream>>>(x, ea, m1w1, m1b1, m1w2, m1b2, m1w3, m1b3,
                                              hidden, msgA, agg, x0T, x1T, eaT,
                                              gcnt, spillCnt, sorted);
    if (sorted) {
        reorder_kernel<<<dim3(TT, NCHUNK), blk, 0, stream>>>(ei, eaT, gcnt, regions,
                                                             spill, spillCnt);
        for (int t = 0; t < TT; ++t) {
            const float* msgIn = (t & 1) ? msgB : msgA;
            float* msgOut = (t & 1) ? msgA : msgB;
            edge_node_kernel<<<NB, dim3(512), 0, stream>>>(
                x0T, x1T, regions, gcnt, spill, spillCnt,
                m1w1, m1b1, m1w2, m1b2, m1w3, m1b3,
                m2w1, m2b1, m2w2, m2b2,
                ow1, ob1, ow2, ob2,
                hidden, msgIn, msgOut, out, t);
        }
    } else {
        for (int t = 0; t < TT; ++t) {
            edge_kernel<<<edgeBlocksLegacy, blk, 0, stream>>>(ei, ea, msgA, agg, t);
            node4_legacy_kernel<<<node4BlocksLegacy, blk, 0, stream>>>(
                x, m1w1, m1b1, m1w2, m1b2, m1w3, m1b3,
                m2w1, m2b1, m2w2, m2b2,
                ow1, ob1, ow2, ob2,
                hidden, msgA, agg, out, t);
        }
    }
}